// Round 12
// baseline (2421.395 us; speedup 1.0000x reference)
//
#include <hip/hip_runtime.h>

// Vanilla RNN: B=64, T=512, I=512, H=1024, O=512.
// k_prep:   W_h fp32 -> bf16 MFMA-B-fragment layout (per-lane contiguous 16B).
// k_inproj: xin = x @ W_in + b_in, stored bf16 re-laid-out as [g][t][16r][1024].
// k_recur:  persistent recurrence, 4 groups x 16 wgs, W_h register-resident.
//           Exchange (r12 = r8 champion + 2 latency cuts):
//             producer: scattered dwordx2 sc1 stores -> PER-WAVE vmcnt ack ->
//                       PER-WAVE flag sc1 (no second barrier; part[] parity-
//                       double-buffered so one __syncthreads per step).
//             consumer: 4-deep PIPELINED narrow flag poll (16 flags = one 64B
//                       line, sampling ~RT/4) -> single 8x1KB coalesced data
//                       sweep (flag => data visible, no retry).
// k_out:    out = h_final @ W_out + b_out (fp32 vector).

typedef float f32x4 __attribute__((ext_vector_type(4)));
typedef short bf16x8 __attribute__((ext_vector_type(8)));
typedef short s16x4 __attribute__((ext_vector_type(4)));
typedef unsigned u32;
typedef unsigned u32x2 __attribute__((ext_vector_type(2)));
typedef unsigned u32x4 __attribute__((ext_vector_type(4)));

__device__ __forceinline__ short f2bf(float f) {
  unsigned u = __builtin_bit_cast(unsigned, f);
  u = (u + 0x7FFFu + ((u >> 16) & 1u)) >> 16;   // RNE
  return (short)u;
}
__device__ __forceinline__ float bf2f(short s) {
  unsigned u = ((unsigned)(unsigned short)s) << 16;
  return __builtin_bit_cast(float, u);
}

// ---------------- Phase 0: W_h fragment prep ------------------------------
__global__ __launch_bounds__(256) void k_prep(const float* __restrict__ Wh,
                                              short* __restrict__ wprep) {
  const int wgid = blockIdx.x;                  // 64 = (cj 16) x (wslot 4)
  const int cj = wgid >> 2, wslot = wgid & 3;
  const int tid = threadIdx.x, lane = tid & 63, sub = tid >> 6;
  const int l15 = lane & 15, lhi = lane >> 4;
  #pragma unroll
  for (int ktl = 0; ktl < 2; ++ktl) {
    int kt = sub * 2 + ktl;
    #pragma unroll
    for (int nt = 0; nt < 4; ++nt) {
      const float* src = Wh + (size_t)(wslot * 256 + kt * 32 + lhi * 8) * 1024
                            + cj * 64 + nt * 16 + l15;
      bf16x8 v;
      #pragma unroll
      for (int j = 0; j < 8; ++j) v[j] = f2bf(src[(size_t)j * 1024]);
      *(bf16x8*)(wprep + ((((size_t)(cj * 4 + wslot) * 8 + kt) * 4 + nt) * 64 + lane) * 8) = v;
    }
  }
}

// ---------------- Phase 1: input projection GEMM --------------------------
// Output layout: xin[((g*512 + t)*16 + r)*1024 + n], g=b>>4, r=b&15, b=m>>9.
__global__ __launch_bounds__(256) void k_inproj(const float* __restrict__ X,
                                                const float* __restrict__ Win,
                                                const float* __restrict__ bin,
                                                short* __restrict__ xin) {
  __shared__ __align__(16) short Al[128][40];
  __shared__ __align__(16) short Bl[128][40];   // stored [n][k]
  __shared__ __align__(16) short Cl[128][64];
  const int m0g = blockIdx.x * 128, n0g = blockIdx.y * 128;
  const int tid = threadIdx.x;
  const int lane = tid & 63, wave = tid >> 6;
  const int wm = (wave & 1) * 64, wn = (wave >> 1) * 64;
  const int l15 = lane & 15, lhi = lane >> 4;

  f32x4 acc[4][4] = {};

  for (int kb = 0; kb < 512; kb += 32) {
    #pragma unroll
    for (int i = 0; i < 4; ++i) {
      int flat = tid + i * 256;
      int row = flat >> 3, k4 = (flat & 7) * 4;
      float4 v = *(const float4*)(X + (size_t)(m0g + row) * 512 + kb + k4);
      s16x4 s; s[0] = f2bf(v.x); s[1] = f2bf(v.y); s[2] = f2bf(v.z); s[3] = f2bf(v.w);
      *(s16x4*)&Al[row][k4] = s;
    }
    #pragma unroll
    for (int i = 0; i < 4; ++i) {
      int flat = tid + i * 256;
      int n = flat & 127, k0 = (flat >> 7) * 4;
      const float* wp = Win + (size_t)(kb + k0) * 1024 + n0g + n;
      s16x4 s;
      s[0] = f2bf(wp[0]); s[1] = f2bf(wp[1024]); s[2] = f2bf(wp[2048]); s[3] = f2bf(wp[3072]);
      *(s16x4*)&Bl[n][k0] = s;
    }
    __syncthreads();
    bf16x8 a[4], b[4];
    #pragma unroll
    for (int mt = 0; mt < 4; ++mt) a[mt] = *(const bf16x8*)&Al[wm + mt * 16 + l15][lhi * 8];
    #pragma unroll
    for (int nt = 0; nt < 4; ++nt) b[nt] = *(const bf16x8*)&Bl[wn + nt * 16 + l15][lhi * 8];
    #pragma unroll
    for (int mt = 0; mt < 4; ++mt)
      #pragma unroll
      for (int nt = 0; nt < 4; ++nt)
        acc[mt][nt] = __builtin_amdgcn_mfma_f32_16x16x32_bf16(a[mt], b[nt], acc[mt][nt], 0, 0, 0);
    __syncthreads();
  }

  float bias[4];
  #pragma unroll
  for (int nt = 0; nt < 4; ++nt) bias[nt] = bin[n0g + wn + nt * 16 + l15];

  const size_t gbase = ((size_t)(m0g >> 13) * 512 + (m0g & 511)) * 16 + ((m0g >> 9) & 15);
  #pragma unroll
  for (int h = 0; h < 2; ++h) {
    if ((wave >> 1) == h) {
      #pragma unroll
      for (int mt = 0; mt < 4; ++mt)
        #pragma unroll
        for (int nt = 0; nt < 4; ++nt)
          #pragma unroll
          for (int r = 0; r < 4; ++r) {
            int row = wm + mt * 16 + lhi * 4 + r;
            Cl[row][nt * 16 + l15] = f2bf(acc[mt][nt][r] + bias[nt]);
          }
    }
    __syncthreads();
    {
      int row = tid >> 1, c0 = (tid & 1) * 32;
      const int4* src = (const int4*)&Cl[row][c0];
      int4* dst = (int4*)(xin + (gbase + (size_t)row * 16) * 1024 + n0g + h * 64 + c0);
      dst[0] = src[0]; dst[1] = src[1]; dst[2] = src[2]; dst[3] = src[3];
    }
    __syncthreads();
  }
}

// ---------------- Phase 2: persistent recurrence --------------------------
// hfrag: bf16[2 parity][4 g][4 kslice][8 kt][64 lane][8 j] = 256 KB.
// Block (p,g,w,kt): A-frag of h rows 0..15, k = w*256+kt*32+(lane>>4)*8+j.
// flags: u32[4 g][16 wg][4 wave]; flag = t means "this producer WAVE's data for
// consuming step t is acked at the MALL". Consumer wave w polls
// flags[g][4w..4w+3][0..3] = 16 consecutive u32 (one 64B line), 4-deep pipelined.
__global__ __launch_bounds__(256, 1) void k_recur(const short* __restrict__ xin,
                                                  const short* __restrict__ wprep,
                                                  const float* __restrict__ bh,
                                                  short* __restrict__ hfrag,
                                                  u32* __restrict__ flags,
                                                  float* __restrict__ hfin) {
  const int wg = blockIdx.x;
  const int g = wg & 3, cj = wg >> 2;
  const int tid = threadIdx.x, lane = tid & 63, wave = tid >> 6;
  const int l15 = lane & 15, lhi = lane >> 4;
  const int colbase = cj << 6, rowbase = g << 4;
  __shared__ __align__(16) float part[2][4][16][68];   // parity double-buffered

  // W_h fragments -> registers/AGPRs, once (asm volatile: un-rematerializable).
  bf16x8 wf[8][4];
  {
    const short* wb = wprep + ((size_t)(cj * 4 + wave) << 14) + lane * 8;
    #pragma unroll
    for (int kt = 0; kt < 8; ++kt)
      #pragma unroll
      for (int nt = 0; nt < 4; ++nt) {
        u32x4 r;
        const short* ap = wb + ((kt * 4 + nt) << 9);
        asm volatile("global_load_dwordx4 %0, %1, off" : "=v"(r) : "v"(ap) : "memory");
        wf[kt][nt] = __builtin_bit_cast(bf16x8, r);
      }
    asm volatile("s_waitcnt vmcnt(0)" ::: "memory");
    __builtin_amdgcn_sched_barrier(0);
  }

  const int erow = tid >> 4, ec0 = (tid & 15) << 2;  // epilogue: row, 4 cols
  const int n0 = colbase + ec0;                      // global column of quad
  const float4 bh4 = *(const float4*)(bh + n0);
  const short* xbase = xin + (size_t)g * 512 * 16384 + erow * 1024 + n0;
  // consumer: 16 per-wave flags in one 64B line (producer wgs 4w..4w+3)
  const u32* fp = flags + (g << 6) + (wave << 4) + (lane & 15);
  u32* myflag = flags + (g << 6) + (cj << 2) + wave;  // this producer wave's flag
  // consumer read bases (parity 0): kt 0..3 from hrd0, kt 4..7 from hrd1
  const short* hrd0 = hfrag + ((g << 2) + wave) * 4096 + lane * 8;
  const short* hrd1 = hrd0 + 2048;                    // +4096 bytes
  // producer store offset (parity 0) for this thread's column quad
  const int wk = n0 >> 8, ktp = (n0 >> 5) & 7, e = n0 & 31;
  const int plane = ((e >> 3) << 4) | erow, pj = n0 & 7;      // pj in {0,4}
  short* hwr = hfrag + (((((g << 2) + wk) << 3) + ktp) << 9) + (plane << 3) + pj;

  // ---- t = 0 peel: h = tanh(bh + xin_0) -> store (parity 1) -> ack -> flag
  {
    s16x4 xs = *(const s16x4*)xbase;
    float h0 = tanhf(bh4.x + bf2f(xs[0]));
    float h1 = tanhf(bh4.y + bf2f(xs[1]));
    float h2 = tanhf(bh4.z + bf2f(xs[2]));
    float h3 = tanhf(bh4.w + bf2f(xs[3]));
    u32x2 wv;
    wv[0] = ((u32)(unsigned short)f2bf(h1) << 16) | (unsigned short)f2bf(h0);
    wv[1] = ((u32)(unsigned short)f2bf(h3) << 16) | (unsigned short)f2bf(h2);
    short* dst = hwr + 65536;                        // parity 1
    asm volatile("global_store_dwordx2 %0, %1, off sc1" :: "v"(dst), "v"(wv) : "memory");
    asm volatile("s_waitcnt vmcnt(0)" ::: "memory"); // this wave's data acked
    __builtin_amdgcn_sched_barrier(0);
    if (lane == 0) {                                 // per-wave flag
      u32 fv = 1;
      asm volatile("global_store_dword %0, %1, off sc1" :: "v"(myflag), "v"(fv) : "memory");
    }
  }

#define POLL_STAGE(fr)                                                      \
  asm volatile("s_waitcnt vmcnt(3)" ::: "memory");                          \
  __builtin_amdgcn_sched_barrier(0);                                        \
  if (__all((int)(fr >= tt))) break;                                        \
  asm volatile("global_load_dword %0, %1, off sc1" : "=v"(fr) : "v"(fp) : "memory");

  // ---- main loop: t = 1..511 ----
  for (int t = 1; t < 512; ++t) {
    const u32 tt = (u32)t;
    // outstanding VMEM at loop top: 1 (this wave's flag store)
    u32x2 xsr;
    {
      const short* xa = xbase + (size_t)t * 16384;
      asm volatile("global_load_dwordx2 %0, %1, off" : "=v"(xsr) : "v"(xa) : "memory");
    }
    u32 f0, f1, f2, f3;
    asm volatile("global_load_dword %0, %1, off sc1" : "=v"(f0) : "v"(fp) : "memory");
    asm volatile("global_load_dword %0, %1, off sc1" : "=v"(f1) : "v"(fp) : "memory");
    asm volatile("global_load_dword %0, %1, off sc1" : "=v"(f2) : "v"(fp) : "memory");
    asm volatile("global_load_dword %0, %1, off sc1" : "=v"(f3) : "v"(fp) : "memory");
    asm volatile("s_waitcnt vmcnt(4)" ::: "memory");   // flag store + xin retired
    __builtin_amdgcn_sched_barrier(0);
    for (;;) {
      POLL_STAGE(f0)
      POLL_STAGE(f1)
      POLL_STAGE(f2)
      POLL_STAGE(f3)
    }
    // single data sweep: 8 coalesced 1KB loads ARE the MFMA A-operands
    const int poff = (t & 1) << 16;
    const short* hs0 = hrd0 + poff;
    const short* hs1 = hrd1 + poff;
    u32x4 ar[8];
    #pragma unroll
    for (int kt = 0; kt < 4; ++kt) {
      asm volatile("global_load_dwordx4 %0, %1, off offset:%c2 sc1"
                   : "=v"(ar[kt]) : "v"(hs0), "i"(kt * 1024) : "memory");
      asm volatile("global_load_dwordx4 %0, %1, off offset:%c2 sc1"
                   : "=v"(ar[kt + 4]) : "v"(hs1), "i"(kt * 1024) : "memory");
    }
    asm volatile("s_waitcnt vmcnt(0)" ::: "memory");   // drains stale polls too
    __builtin_amdgcn_sched_barrier(0);

    f32x4 acc[4] = {};
    #pragma unroll
    for (int kt = 0; kt < 8; ++kt) {
      bf16x8 a = __builtin_bit_cast(bf16x8, ar[kt]);
      #pragma unroll
      for (int nt = 0; nt < 4; ++nt)
        acc[nt] = __builtin_amdgcn_mfma_f32_16x16x32_bf16(a, wf[kt][nt], acc[nt], 0, 0, 0);
    }
    const int p = t & 1;
    #pragma unroll
    for (int nt = 0; nt < 4; ++nt)
      #pragma unroll
      for (int rr = 0; rr < 4; ++rr)
        part[p][wave][lhi * 4 + rr][nt * 16 + l15] = acc[nt][rr];
    __syncthreads();   // single barrier per step (parity-buffered partials)

    f32x4 p0 = *(const f32x4*)&part[p][0][erow][ec0];
    f32x4 p1 = *(const f32x4*)&part[p][1][erow][ec0];
    f32x4 p2 = *(const f32x4*)&part[p][2][erow][ec0];
    f32x4 p3 = *(const f32x4*)&part[p][3][erow][ec0];
    f32x4 ps = (p0 + p1) + (p2 + p3);
    s16x4 xs = __builtin_bit_cast(s16x4, xsr);
    float h0 = tanhf(ps[0] + bh4.x + bf2f(xs[0]));
    float h1 = tanhf(ps[1] + bh4.y + bf2f(xs[1]));
    float h2 = tanhf(ps[2] + bh4.z + bf2f(xs[2]));
    float h3 = tanhf(ps[3] + bh4.w + bf2f(xs[3]));

    if (t < 511) {
      u32x2 wv;
      wv[0] = ((u32)(unsigned short)f2bf(h1) << 16) | (unsigned short)f2bf(h0);
      wv[1] = ((u32)(unsigned short)f2bf(h3) << 16) | (unsigned short)f2bf(h2);
      short* dst = hwr + (((t + 1) & 1) << 16);
      asm volatile("global_store_dwordx2 %0, %1, off sc1" :: "v"(dst), "v"(wv) : "memory");
      asm volatile("s_waitcnt vmcnt(0)" ::: "memory"); // PER-WAVE ack (no barrier)
      __builtin_amdgcn_sched_barrier(0);
      if (lane == 0) {                                 // per-wave flag
        u32 fv = (u32)(t + 1);
        asm volatile("global_store_dword %0, %1, off sc1" :: "v"(myflag), "v"(fv) : "memory");
      }
    } else {
      float4 hf4; hf4.x = h0; hf4.y = h1; hf4.z = h2; hf4.w = h3;
      *(float4*)(hfin + (rowbase + erow) * 1024 + n0) = hf4;
    }
  }
#undef POLL_STAGE
}

// ---------------- Phase 3: output projection ------------------------------
__global__ __launch_bounds__(256) void k_out(const float* __restrict__ hfin,
                                             const float* __restrict__ Wout,
                                             const float* __restrict__ bout,
                                             float* __restrict__ out) {
  __shared__ __align__(16) float hrow[1024];
  const int b = blockIdx.x >> 1;
  const int c0 = (blockIdx.x & 1) << 8;
  const int tid = threadIdx.x;
  #pragma unroll
  for (int i = 0; i < 4; ++i) hrow[tid + i * 256] = hfin[b * 1024 + tid + i * 256];
  __syncthreads();
  const int col = c0 + tid;
  const float* wp = Wout + col;
  float a0 = bout[col], a1 = 0, a2 = 0, a3 = 0, a4 = 0, a5 = 0, a6 = 0, a7 = 0;
  #pragma unroll 4
  for (int k = 0; k < 1024; k += 8) {
    a0 += hrow[k + 0] * wp[(size_t)(k + 0) * 512];
    a1 += hrow[k + 1] * wp[(size_t)(k + 1) * 512];
    a2 += hrow[k + 2] * wp[(size_t)(k + 2) * 512];
    a3 += hrow[k + 3] * wp[(size_t)(k + 3) * 512];
    a4 += hrow[k + 4] * wp[(size_t)(k + 4) * 512];
    a5 += hrow[k + 5] * wp[(size_t)(k + 5) * 512];
    a6 += hrow[k + 6] * wp[(size_t)(k + 6) * 512];
    a7 += hrow[k + 7] * wp[(size_t)(k + 7) * 512];
  }
  out[b * 512 + col] = ((a0 + a1) + (a2 + a3)) + ((a4 + a5) + (a6 + a7));
}

// ---------------- launch --------------------------------------------------
extern "C" void kernel_launch(void* const* d_in, const int* in_sizes, int n_in,
                              void* d_out, int out_size, void* d_ws, size_t ws_size,
                              hipStream_t stream) {
  const float* x    = (const float*)d_in[0];
  const float* Win  = (const float*)d_in[1];
  const float* bin  = (const float*)d_in[2];
  const float* Wh   = (const float*)d_in[3];
  const float* bh   = (const float*)d_in[4];
  const float* Wout = (const float*)d_in[5];
  const float* bout = (const float*)d_in[6];

  char* ws = (char*)d_ws;
  short* xin   = (short*)ws;                   // 67,108,864 B (re-laid-out)
  short* wprep = (short*)(ws + 67108864);      // 2 MB fragments
  short* hfrag = (short*)(ws + 69206016);      // 256 KB h fragments (2 parities)
  u32*   flags = (u32*)(ws + 69468160);        // 4*64 u32, padded to 1 KiB
  float* hfin  = (float*)(ws + 69469184);      // 256 KB

  hipMemsetAsync(flags, 0, 1024, stream);      // replay-deterministic
  hipLaunchKernelGGL(k_prep, dim3(64), dim3(256), 0, stream, Wh, wprep);
  hipLaunchKernelGGL(k_inproj, dim3(256, 8), dim3(256), 0, stream, x, Win, bin, xin);
  hipLaunchKernelGGL(k_recur, dim3(64), dim3(256), 0, stream,
                     xin, wprep, bh, hfrag, flags, hfin);
  hipLaunchKernelGGL(k_out, dim3(128), dim3(256), 0, stream, hfin, Wout, bout, (float*)d_out);
}

// Round 13
// 1294.611 us; speedup vs baseline: 1.8704x; 1.8704x over previous
//
#include <hip/hip_runtime.h>

// Vanilla RNN: B=64, T=512, I=512, H=1024, O=512.
// k_prep:   W_h fp32 -> bf16 MFMA-B-fragment layout (per-lane contiguous 16B).
// k_inproj: xin = x @ W_in + b_in, stored bf16 re-laid-out as [g][t][16r][1024].
// k_recur:  persistent recurrence, 4 groups x 16 wgs, W_h register-resident.
//           r13 = r8 champion + REPLICATED FLAGS (de-hotspot): producer wg
//           publishes its flag into 16 consumer-private 64B-padded slots
//           (tid<16, 16 distinct lines, fire-and-forget after wg-wide data
//           ack + barrier). Consumer wave polls ITS OWN line (4 flags,
//           1 reader + 4 writers) -> no shared hot MALL line.
//           Data path identical to r8: scattered dwordx2 sc1 stores ->
//           per-wave vmcnt ack -> barrier -> flags; consumer narrow poll ->
//           8x1KB coalesced dwordx4 sc1 sweep = MFMA A-fragments.
// k_out:    out = h_final @ W_out + b_out (fp32 vector).

typedef float f32x4 __attribute__((ext_vector_type(4)));
typedef short bf16x8 __attribute__((ext_vector_type(8)));
typedef short s16x4 __attribute__((ext_vector_type(4)));
typedef unsigned u32;
typedef unsigned u32x2 __attribute__((ext_vector_type(2)));
typedef unsigned u32x4 __attribute__((ext_vector_type(4)));

__device__ __forceinline__ short f2bf(float f) {
  unsigned u = __builtin_bit_cast(unsigned, f);
  u = (u + 0x7FFFu + ((u >> 16) & 1u)) >> 16;   // RNE
  return (short)u;
}
__device__ __forceinline__ float bf2f(short s) {
  unsigned u = ((unsigned)(unsigned short)s) << 16;
  return __builtin_bit_cast(float, u);
}

// ---------------- Phase 0: W_h fragment prep ------------------------------
__global__ __launch_bounds__(256) void k_prep(const float* __restrict__ Wh,
                                              short* __restrict__ wprep) {
  const int wgid = blockIdx.x;                  // 64 = (cj 16) x (wslot 4)
  const int cj = wgid >> 2, wslot = wgid & 3;
  const int tid = threadIdx.x, lane = tid & 63, sub = tid >> 6;
  const int l15 = lane & 15, lhi = lane >> 4;
  #pragma unroll
  for (int ktl = 0; ktl < 2; ++ktl) {
    int kt = sub * 2 + ktl;
    #pragma unroll
    for (int nt = 0; nt < 4; ++nt) {
      const float* src = Wh + (size_t)(wslot * 256 + kt * 32 + lhi * 8) * 1024
                            + cj * 64 + nt * 16 + l15;
      bf16x8 v;
      #pragma unroll
      for (int j = 0; j < 8; ++j) v[j] = f2bf(src[(size_t)j * 1024]);
      *(bf16x8*)(wprep + ((((size_t)(cj * 4 + wslot) * 8 + kt) * 4 + nt) * 64 + lane) * 8) = v;
    }
  }
}

// ---------------- Phase 1: input projection GEMM --------------------------
// Output layout: xin[((g*512 + t)*16 + r)*1024 + n], g=b>>4, r=b&15, b=m>>9.
__global__ __launch_bounds__(256) void k_inproj(const float* __restrict__ X,
                                                const float* __restrict__ Win,
                                                const float* __restrict__ bin,
                                                short* __restrict__ xin) {
  __shared__ __align__(16) short Al[128][40];
  __shared__ __align__(16) short Bl[128][40];   // stored [n][k]
  __shared__ __align__(16) short Cl[128][64];
  const int m0g = blockIdx.x * 128, n0g = blockIdx.y * 128;
  const int tid = threadIdx.x;
  const int lane = tid & 63, wave = tid >> 6;
  const int wm = (wave & 1) * 64, wn = (wave >> 1) * 64;
  const int l15 = lane & 15, lhi = lane >> 4;

  f32x4 acc[4][4] = {};

  for (int kb = 0; kb < 512; kb += 32) {
    #pragma unroll
    for (int i = 0; i < 4; ++i) {
      int flat = tid + i * 256;
      int row = flat >> 3, k4 = (flat & 7) * 4;
      float4 v = *(const float4*)(X + (size_t)(m0g + row) * 512 + kb + k4);
      s16x4 s; s[0] = f2bf(v.x); s[1] = f2bf(v.y); s[2] = f2bf(v.z); s[3] = f2bf(v.w);
      *(s16x4*)&Al[row][k4] = s;
    }
    #pragma unroll
    for (int i = 0; i < 4; ++i) {
      int flat = tid + i * 256;
      int n = flat & 127, k0 = (flat >> 7) * 4;
      const float* wp = Win + (size_t)(kb + k0) * 1024 + n0g + n;
      s16x4 s;
      s[0] = f2bf(wp[0]); s[1] = f2bf(wp[1024]); s[2] = f2bf(wp[2048]); s[3] = f2bf(wp[3072]);
      *(s16x4*)&Bl[n][k0] = s;
    }
    __syncthreads();
    bf16x8 a[4], b[4];
    #pragma unroll
    for (int mt = 0; mt < 4; ++mt) a[mt] = *(const bf16x8*)&Al[wm + mt * 16 + l15][lhi * 8];
    #pragma unroll
    for (int nt = 0; nt < 4; ++nt) b[nt] = *(const bf16x8*)&Bl[wn + nt * 16 + l15][lhi * 8];
    #pragma unroll
    for (int mt = 0; mt < 4; ++mt)
      #pragma unroll
      for (int nt = 0; nt < 4; ++nt)
        acc[mt][nt] = __builtin_amdgcn_mfma_f32_16x16x32_bf16(a[mt], b[nt], acc[mt][nt], 0, 0, 0);
    __syncthreads();
  }

  float bias[4];
  #pragma unroll
  for (int nt = 0; nt < 4; ++nt) bias[nt] = bin[n0g + wn + nt * 16 + l15];

  const size_t gbase = ((size_t)(m0g >> 13) * 512 + (m0g & 511)) * 16 + ((m0g >> 9) & 15);
  #pragma unroll
  for (int h = 0; h < 2; ++h) {
    if ((wave >> 1) == h) {
      #pragma unroll
      for (int mt = 0; mt < 4; ++mt)
        #pragma unroll
        for (int nt = 0; nt < 4; ++nt)
          #pragma unroll
          for (int r = 0; r < 4; ++r) {
            int row = wm + mt * 16 + lhi * 4 + r;
            Cl[row][nt * 16 + l15] = f2bf(acc[mt][nt][r] + bias[nt]);
          }
    }
    __syncthreads();
    {
      int row = tid >> 1, c0 = (tid & 1) * 32;
      const int4* src = (const int4*)&Cl[row][c0];
      int4* dst = (int4*)(xin + (gbase + (size_t)row * 16) * 1024 + n0g + h * 64 + c0);
      dst[0] = src[0]; dst[1] = src[1]; dst[2] = src[2]; dst[3] = src[3];
    }
    __syncthreads();
  }
}

// ---------------- Phase 2: persistent recurrence --------------------------
// hfrag: bf16[2 parity][4 g][4 kslice][8 kt][64 lane][8 j] = 256 KB.
// Block (p,g,w,kt): A-frag of h rows 0..15, k = w*256+kt*32+(lane>>4)*8+j.
// flags (REPLICATED): u32[4 g][16 cc][4 w][16 pad]; line (g,cc,w) is polled by
// exactly ONE consumer wave (wave w of wg cc) and written by its 4 producers
// (wgs 4w..4w+3, slot p=j&3). flag = t means "producer wg j's data for
// consuming step t is acked at the MALL".
__global__ __launch_bounds__(256, 1) void k_recur(const short* __restrict__ xin,
                                                  const short* __restrict__ wprep,
                                                  const float* __restrict__ bh,
                                                  short* __restrict__ hfrag,
                                                  u32* __restrict__ flags,
                                                  float* __restrict__ hfin) {
  const int wg = blockIdx.x;
  const int g = wg & 3, cj = wg >> 2;
  const int tid = threadIdx.x, lane = tid & 63, wave = tid >> 6;
  const int l15 = lane & 15, lhi = lane >> 4;
  const int colbase = cj << 6, rowbase = g << 4;
  __shared__ __align__(16) float part[4][16][68];

  // W_h fragments -> registers/AGPRs, once (asm volatile: un-rematerializable).
  bf16x8 wf[8][4];
  {
    const short* wb = wprep + ((size_t)(cj * 4 + wave) << 14) + lane * 8;
    #pragma unroll
    for (int kt = 0; kt < 8; ++kt)
      #pragma unroll
      for (int nt = 0; nt < 4; ++nt) {
        u32x4 r;
        const short* ap = wb + ((kt * 4 + nt) << 9);
        asm volatile("global_load_dwordx4 %0, %1, off" : "=v"(r) : "v"(ap) : "memory");
        wf[kt][nt] = __builtin_bit_cast(bf16x8, r);
      }
    asm volatile("s_waitcnt vmcnt(0)" ::: "memory");
    __builtin_amdgcn_sched_barrier(0);
  }

  const int erow = tid >> 4, ec0 = (tid & 15) << 2;  // epilogue: row, 4 cols
  const int n0 = colbase + ec0;                      // global column of quad
  const float4 bh4 = *(const float4*)(bh + n0);
  const short* xbase = xin + (size_t)g * 512 * 16384 + erow * 1024 + n0;
  // consumer: private flag line (g, cj, wave); 4 producer flags in 16B
  const u32* fp = flags + (g << 10) + (cj << 6) + (wave << 4) + (lane & 3);
  // producer: 16 replicated flag slots, thread tid<16 writes copy cc=tid
  u32* myflag = flags + (g << 10) + (tid << 6) + ((cj >> 2) << 4) + (cj & 3);
  // consumer read bases (parity 0): kt 0..3 from hrd0, kt 4..7 from hrd1
  const short* hrd0 = hfrag + ((g << 2) + wave) * 4096 + lane * 8;
  const short* hrd1 = hrd0 + 2048;                   // +4096 bytes
  // producer store offset (parity 0) for this thread's column quad
  const int wk = n0 >> 8, ktp = (n0 >> 5) & 7, e = n0 & 31;
  const int plane = ((e >> 3) << 4) | erow, pj = n0 & 7;      // pj in {0,4}
  short* hwr = hfrag + (((((g << 2) + wk) << 3) + ktp) << 9) + (plane << 3) + pj;

  // ---- t = 0 peel: h = tanh(bh + xin_0) -> store (parity 1) -> ack -> flags
  {
    s16x4 xs = *(const s16x4*)xbase;
    float h0 = tanhf(bh4.x + bf2f(xs[0]));
    float h1 = tanhf(bh4.y + bf2f(xs[1]));
    float h2 = tanhf(bh4.z + bf2f(xs[2]));
    float h3 = tanhf(bh4.w + bf2f(xs[3]));
    u32x2 wv;
    wv[0] = ((u32)(unsigned short)f2bf(h1) << 16) | (unsigned short)f2bf(h0);
    wv[1] = ((u32)(unsigned short)f2bf(h3) << 16) | (unsigned short)f2bf(h2);
    short* dst = hwr + 65536;                        // parity 1
    asm volatile("global_store_dwordx2 %0, %1, off sc1" :: "v"(dst), "v"(wv) : "memory");
    asm volatile("s_waitcnt vmcnt(0)" ::: "memory");
    __syncthreads();                                 // all 4 waves' data acked
    if (tid < 16) {                                  // 16 replicated flag copies
      u32 fv = 1;
      asm volatile("global_store_dword %0, %1, off sc1" :: "v"(myflag), "v"(fv) : "memory");
    }
  }

  // ---- main loop: t = 1..511 ----
  for (int t = 1; t < 512; ++t) {
    s16x4 xs = *(const s16x4*)(xbase + (size_t)t * 16384);
    // 1) poll: one private 64B flag line per wave per iteration
    for (;;) {
      u32 f;
      asm volatile("global_load_dword %0, %1, off sc1\n\ts_waitcnt vmcnt(0)"
                   : "=v"(f) : "v"(fp) : "memory");
      __builtin_amdgcn_sched_barrier(0);
      if (__all((int)(f >= (u32)t))) break;
    }
    // 2) 8 coalesced 1KB fragment loads — these ARE the MFMA A-operands
    const int poff = (t & 1) << 16;
    const short* hs0 = hrd0 + poff;
    const short* hs1 = hrd1 + poff;
    u32x4 ar[8];
    #pragma unroll
    for (int kt = 0; kt < 4; ++kt) {
      asm volatile("global_load_dwordx4 %0, %1, off offset:%c2 sc1"
                   : "=v"(ar[kt]) : "v"(hs0), "i"(kt * 1024) : "memory");
      asm volatile("global_load_dwordx4 %0, %1, off offset:%c2 sc1"
                   : "=v"(ar[kt + 4]) : "v"(hs1), "i"(kt * 1024) : "memory");
    }
    asm volatile("s_waitcnt vmcnt(0)" ::: "memory");
    __builtin_amdgcn_sched_barrier(0);

    f32x4 acc[4] = {};
    #pragma unroll
    for (int kt = 0; kt < 8; ++kt) {
      bf16x8 a = __builtin_bit_cast(bf16x8, ar[kt]);
      #pragma unroll
      for (int nt = 0; nt < 4; ++nt)
        acc[nt] = __builtin_amdgcn_mfma_f32_16x16x32_bf16(a, wf[kt][nt], acc[nt], 0, 0, 0);
    }
    #pragma unroll
    for (int nt = 0; nt < 4; ++nt)
      #pragma unroll
      for (int rr = 0; rr < 4; ++rr)
        part[wave][lhi * 4 + rr][nt * 16 + l15] = acc[nt][rr];
    __syncthreads();                                 // barrier 1: partials ready

    f32x4 p0 = *(const f32x4*)&part[0][erow][ec0];
    f32x4 p1 = *(const f32x4*)&part[1][erow][ec0];
    f32x4 p2 = *(const f32x4*)&part[2][erow][ec0];
    f32x4 p3 = *(const f32x4*)&part[3][erow][ec0];
    f32x4 ps = (p0 + p1) + (p2 + p3);
    float h0 = tanhf(ps[0] + bh4.x + bf2f(xs[0]));
    float h1 = tanhf(ps[1] + bh4.y + bf2f(xs[1]));
    float h2 = tanhf(ps[2] + bh4.z + bf2f(xs[2]));
    float h3 = tanhf(ps[3] + bh4.w + bf2f(xs[3]));

    if (t < 511) {
      u32x2 wv;
      wv[0] = ((u32)(unsigned short)f2bf(h1) << 16) | (unsigned short)f2bf(h0);
      wv[1] = ((u32)(unsigned short)f2bf(h3) << 16) | (unsigned short)f2bf(h2);
      short* dst = hwr + (((t + 1) & 1) << 16);
      asm volatile("global_store_dwordx2 %0, %1, off sc1" :: "v"(dst), "v"(wv) : "memory");
      asm volatile("s_waitcnt vmcnt(0)" ::: "memory");   // this wave's data acked
      __syncthreads();                                   // barrier 2: wg acked
      if (tid < 16) {                                    // 16 replicated copies
        u32 fv = (u32)(t + 1);
        asm volatile("global_store_dword %0, %1, off sc1" :: "v"(myflag), "v"(fv) : "memory");
      }
    } else {
      float4 hf4; hf4.x = h0; hf4.y = h1; hf4.z = h2; hf4.w = h3;
      *(float4*)(hfin + (rowbase + erow) * 1024 + n0) = hf4;
      __syncthreads();
    }
  }
}

// ---------------- Phase 3: output projection ------------------------------
__global__ __launch_bounds__(256) void k_out(const float* __restrict__ hfin,
                                             const float* __restrict__ Wout,
                                             const float* __restrict__ bout,
                                             float* __restrict__ out) {
  __shared__ __align__(16) float hrow[1024];
  const int b = blockIdx.x >> 1;
  const int c0 = (blockIdx.x & 1) << 8;
  const int tid = threadIdx.x;
  #pragma unroll
  for (int i = 0; i < 4; ++i) hrow[tid + i * 256] = hfin[b * 1024 + tid + i * 256];
  __syncthreads();
  const int col = c0 + tid;
  const float* wp = Wout + col;
  float a0 = bout[col], a1 = 0, a2 = 0, a3 = 0, a4 = 0, a5 = 0, a6 = 0, a7 = 0;
  #pragma unroll 4
  for (int k = 0; k < 1024; k += 8) {
    a0 += hrow[k + 0] * wp[(size_t)(k + 0) * 512];
    a1 += hrow[k + 1] * wp[(size_t)(k + 1) * 512];
    a2 += hrow[k + 2] * wp[(size_t)(k + 2) * 512];
    a3 += hrow[k + 3] * wp[(size_t)(k + 3) * 512];
    a4 += hrow[k + 4] * wp[(size_t)(k + 4) * 512];
    a5 += hrow[k + 5] * wp[(size_t)(k + 5) * 512];
    a6 += hrow[k + 6] * wp[(size_t)(k + 6) * 512];
    a7 += hrow[k + 7] * wp[(size_t)(k + 7) * 512];
  }
  out[b * 512 + col] = ((a0 + a1) + (a2 + a3)) + ((a4 + a5) + (a6 + a7));
}

// ---------------- launch --------------------------------------------------
extern "C" void kernel_launch(void* const* d_in, const int* in_sizes, int n_in,
                              void* d_out, int out_size, void* d_ws, size_t ws_size,
                              hipStream_t stream) {
  const float* x    = (const float*)d_in[0];
  const float* Win  = (const float*)d_in[1];
  const float* bin  = (const float*)d_in[2];
  const float* Wh   = (const float*)d_in[3];
  const float* bh   = (const float*)d_in[4];
  const float* Wout = (const float*)d_in[5];
  const float* bout = (const float*)d_in[6];

  char* ws = (char*)d_ws;
  short* xin   = (short*)ws;                   // 67,108,864 B (re-laid-out)
  short* wprep = (short*)(ws + 67108864);      // 2 MB fragments
  short* hfrag = (short*)(ws + 69206016);      // 256 KB h fragments (2 parities)
  u32*   flags = (u32*)(ws + 69468160);        // 16 KB replicated flags
  float* hfin  = (float*)(ws + 69484544);      // 256 KB

  hipMemsetAsync(flags, 0, 16384, stream);     // replay-deterministic
  hipLaunchKernelGGL(k_prep, dim3(64), dim3(256), 0, stream, Wh, wprep);
  hipLaunchKernelGGL(k_inproj, dim3(256, 8), dim3(256), 0, stream, x, Win, bin, xin);
  hipLaunchKernelGGL(k_recur, dim3(64), dim3(256), 0, stream,
                     xin, wprep, bh, hfrag, flags, hfin);
  hipLaunchKernelGGL(k_out, dim3(128), dim3(256), 0, stream, hfin, Wout, bout, (float*)d_out);
}